// Round 3
// baseline (4548.797 us; speedup 1.0000x reference)
//
#include <hip/hip_runtime.h>
#include <math.h>

// Soft k-means via bf16 hi/lo 3-product MFMA emulation of fp32.
// N=100000, D=512, K=256, temp=30, 11 iterations.
//
// v4: dist uses SWAPPED MFMA operands (A=mu, B=data) so r falls out in
// [k][i] layout -> fully coalesced plane stores (no transpose, no scatter).
// Both GEMM kernels stage via global_load_lds (16B) into linear unpadded
// hi/lo LDS arrays (64B rows -> bank-uniform 16B fragment reads).
// r is stored as two bf16 planes [k][i] so update staging is a pure
// linear async copy (no v_perm unpack). Fallback: round-0 baseline.

#define DIMD 512
#define KCL 256
#define NSPLIT 96   // baseline update i-splits (fallback)
#define NCH4 128    // v4 update i-chunks (chunk rounded to 32)

typedef __attribute__((ext_vector_type(8))) short short8;
typedef __attribute__((ext_vector_type(4))) short short4v;
typedef __attribute__((ext_vector_type(4))) float float4v;

typedef __attribute__((address_space(1))) void* gas1_t;
typedef __attribute__((address_space(3))) void* las3_t;
__device__ __forceinline__ void glds16(const void* g, void* l) {
  __builtin_amdgcn_global_load_lds((gas1_t)g, (las3_t)l, 16, 0, 0);
}

__device__ __forceinline__ short f2bf(float x) {
  union { float f; unsigned u; } v; v.f = x;
  unsigned r = v.u + 0x7fff + ((v.u >> 16) & 1);   // round-to-nearest-even
  return (short)(r >> 16);
}
__device__ __forceinline__ float bf2f(short b) {
  union { unsigned u; float f; } v;
  v.u = ((unsigned)(unsigned short)b) << 16;
  return v.f;
}

// -------- row norms of data + optional [i][d] hi/lo planes --------
__global__ void row_norms_conv_k(const float* __restrict__ x,
                                 float* __restrict__ inv_norm,
                                 short* __restrict__ pl_hi,
                                 short* __restrict__ pl_lo, int n,
                                 int do_planes) {
  int wave = threadIdx.x >> 6;
  int lane = threadIdx.x & 63;
  int row = blockIdx.x * 4 + wave;
  if (row >= n) return;
  const float* p = x + (size_t)row * DIMD + lane * 8;
  float4 a = *(const float4*)p;
  float4 b = *(const float4*)(p + 4);
  float s = a.x*a.x + a.y*a.y + a.z*a.z + a.w*a.w
          + b.x*b.x + b.y*b.y + b.z*b.z + b.w*b.w;
#pragma unroll
  for (int m = 32; m >= 1; m >>= 1) s += __shfl_xor(s, m);
  float inv = 1.0f / (sqrtf(s) + 1e-6f);
  if (lane == 0) inv_norm[row] = inv;
  if (do_planes) {
    float vv[8] = {a.x*inv, a.y*inv, a.z*inv, a.w*inv,
                   b.x*inv, b.y*inv, b.z*inv, b.w*inv};
    short8 hv, lv;
#pragma unroll
    for (int j = 0; j < 8; ++j) {
      short h = f2bf(vv[j]);
      hv[j] = h;
      lv[j] = f2bf(vv[j] - bf2f(h));
    }
    *(short8*)(pl_hi + (size_t)row * DIMD + lane * 8) = hv;
    *(short8*)(pl_lo + (size_t)row * DIMD + lane * 8) = lv;
  }
}

// -------- normalized data -> transposed hi/lo planes [d][i] --------
__global__ __launch_bounds__(256) void transpose_k(
    const float* __restrict__ x, const float* __restrict__ inv_norm,
    short* __restrict__ xT_hi, short* __restrict__ xT_lo, int n) {
  __shared__ unsigned lds[64][65];  // packed (hi<<16|lo), [d][i], +1 pad
  int t = threadIdx.x;
  int i0 = blockIdx.x * 64, d0 = blockIdx.y * 64;
  {
    int il = t >> 2, seg = (t & 3) * 16;
    int gi = i0 + il; if (gi > n - 1) gi = n - 1;
    float sc = inv_norm[gi];
    const float* p = x + (size_t)gi * DIMD + d0 + seg;
    float4 f0 = *(const float4*)p;
    float4 f1 = *(const float4*)(p + 4);
    float4 f2 = *(const float4*)(p + 8);
    float4 f3 = *(const float4*)(p + 12);
    float vv[16] = {f0.x,f0.y,f0.z,f0.w, f1.x,f1.y,f1.z,f1.w,
                    f2.x,f2.y,f2.z,f2.w, f3.x,f3.y,f3.z,f3.w};
#pragma unroll
    for (int j = 0; j < 16; ++j) {
      float v = vv[j] * sc;
      short h = f2bf(v);
      short l = f2bf(v - bf2f(h));
      lds[seg + j][il] =
          ((unsigned)(unsigned short)h << 16) | (unsigned short)l;
    }
  }
  __syncthreads();
  {
    int dl = t >> 2, isg = (t & 3) * 16;
    if (i0 + isg < n) {  // n % 16 == 0
      unsigned u[16];
#pragma unroll
      for (int j = 0; j < 16; ++j) u[j] = lds[dl][isg + j];
      union S8u { short8 s; unsigned w[4]; };
      S8u h0, h1, l0, l1;
#pragma unroll
      for (int j = 0; j < 4; ++j) {
        h0.w[j] = __builtin_amdgcn_perm(u[2*j+1], u[2*j], 0x07060302u);
        l0.w[j] = __builtin_amdgcn_perm(u[2*j+1], u[2*j], 0x05040100u);
        h1.w[j] = __builtin_amdgcn_perm(u[2*j+9], u[2*j+8], 0x07060302u);
        l1.w[j] = __builtin_amdgcn_perm(u[2*j+9], u[2*j+8], 0x05040100u);
      }
      size_t rb = (size_t)(d0 + dl) * n + i0 + isg;
      *(short8*)(xT_hi + rb) = h0.s;
      *(short8*)(xT_hi + rb + 8) = h1.s;
      *(short8*)(xT_lo + rb) = l0.s;
      *(short8*)(xT_lo + rb + 8) = l1.s;
    }
  }
}

// -------- mu_n = normalize(mu_src [/ colsum]) -> bf16 hi/lo; zero accums ----
__global__ void mu_norm_k(const float* __restrict__ mu_src,
                          const float* __restrict__ colsum_in,
                          short* __restrict__ mu_hi, short* __restrict__ mu_lo,
                          float* __restrict__ mu_acc_z,
                          float* __restrict__ colsum_z, int use_colsum) {
  int k = blockIdx.x;
  int t = threadIdx.x;
  float inv_c = 1.0f;
  if (use_colsum) inv_c = 1.0f / colsum_in[k];
  float v0 = mu_src[k * DIMD + t] * inv_c;
  float v1 = mu_src[k * DIMD + t + 256] * inv_c;
  float s = v0 * v0 + v1 * v1;
#pragma unroll
  for (int m = 32; m >= 1; m >>= 1) s += __shfl_xor(s, m);
  __shared__ float sred[4];
  int lane = t & 63, wv = t >> 6;
  if (lane == 0) sred[wv] = s;
  __syncthreads();
  s = sred[0] + sred[1] + sred[2] + sred[3];
  float inv = 1.0f / (sqrtf(s) + 1e-6f);
  float w0 = v0 * inv, w1 = v1 * inv;
  short h0 = f2bf(w0), h1 = f2bf(w1);
  mu_hi[k * DIMD + t] = h0;
  mu_hi[k * DIMD + t + 256] = h1;
  mu_lo[k * DIMD + t] = f2bf(w0 - bf2f(h0));
  mu_lo[k * DIMD + t + 256] = f2bf(w1 - bf2f(h1));
  mu_acc_z[k * DIMD + t] = 0.0f;
  mu_acc_z[k * DIMD + t + 256] = 0.0f;
  if (t == 0) colsum_z[k] = 0.0f;
}

// -------- out_mu = mu_acc / colsum --------
__global__ void final_mu_k(const float* __restrict__ mu_acc,
                           const float* __restrict__ colsum,
                           float* __restrict__ out) {
  int k = blockIdx.x;
  int t = threadIdx.x;
  float ic = 1.0f / colsum[k];
  out[k * DIMD + t] = mu_acc[k * DIMD + t] * ic;
  out[k * DIMD + t + 256] = mu_acc[k * DIMD + t + 256] * ic;
}

// -------- dist v4: SWAPPED operands; A=mu (M=k), B=data (N=i) --------
// Block: 256 k x 64 i, 4 waves; wave w owns k rows w*64..+63 (4x4 MFMA
// tiles). r stores land coalesced in [k][i] bf16 hi/lo planes.
// Staging: global_load_lds 16B into linear hi/lo LDS arrays (64B rows).
__global__ __launch_bounds__(256) void dist_v4_k(
    const short* __restrict__ pl_hi, const short* __restrict__ pl_lo,
    const short* __restrict__ mu_hi, const short* __restrict__ mu_lo,
    short* __restrict__ r_hi, short* __restrict__ r_lo,
    float* __restrict__ r_f32, int write_f32,
    float* __restrict__ colsum, const float* __restrict__ temp_p, int n) {
  __shared__ __align__(16) short a_hi[64 * 32], a_lo[64 * 32];    // data tile
  __shared__ __align__(16) short b_hi[256 * 32], b_lo[256 * 32];  // mu tile
  __shared__ __align__(16) float red[64][4];

  int t = threadIdx.x, wave = t >> 6, lane = t & 63;
  int q = lane >> 4, lx = lane & 15;
  int i0 = blockIdx.x * 64;

  // staging address setup (lane-linear: row = lane>>2, seg = lane&3)
  int srow = lane >> 2;
  int seg8 = (lane & 3) * 8;  // shorts
  int gi_s = i0 + wave * 16 + srow;
  if (gi_s > n - 1) gi_s = n - 1;
  const short* asr_h = pl_hi + (size_t)gi_s * DIMD + seg8;
  const short* asr_l = pl_lo + (size_t)gi_s * DIMD + seg8;
  short* adst_h = a_hi + wave * 512;
  short* adst_l = a_lo + wave * 512;
  const short* bsr_h[4];
  const short* bsr_l[4];
  short* bdst_h[4];
  short* bdst_l[4];
#pragma unroll
  for (int c = 0; c < 4; ++c) {
    int kr = c * 64 + wave * 16 + srow;
    bsr_h[c] = mu_hi + (size_t)kr * DIMD + seg8;
    bsr_l[c] = mu_lo + (size_t)kr * DIMD + seg8;
    bdst_h[c] = b_hi + (c * 64 + wave * 16) * 32;
    bdst_l[c] = b_lo + (c * 64 + wave * 16) * 32;
  }

  float4v acc[4][4];
#pragma unroll
  for (int mt = 0; mt < 4; ++mt)
#pragma unroll
    for (int nt = 0; nt < 4; ++nt) acc[mt][nt] = (float4v)0.0f;

  for (int ch = 0; ch < 16; ++ch) {
    int d0 = ch * 32;
    glds16(asr_h + d0, adst_h);
    glds16(asr_l + d0, adst_l);
#pragma unroll
    for (int c = 0; c < 4; ++c) {
      glds16(bsr_h[c] + d0, bdst_h[c]);
      glds16(bsr_l[c] + d0, bdst_l[c]);
    }
    __syncthreads();
    short8 mh[4], ml[4], dh[4], dl[4];
#pragma unroll
    for (int mt = 0; mt < 4; ++mt) {
      int kr = wave * 64 + mt * 16 + lx;
      mh[mt] = *(const short8*)&b_hi[kr * 32 + q * 8];
      ml[mt] = *(const short8*)&b_lo[kr * 32 + q * 8];
    }
#pragma unroll
    for (int nt = 0; nt < 4; ++nt) {
      int ir = nt * 16 + lx;
      dh[nt] = *(const short8*)&a_hi[ir * 32 + q * 8];
      dl[nt] = *(const short8*)&a_lo[ir * 32 + q * 8];
    }
#pragma unroll
    for (int mt = 0; mt < 4; ++mt)
#pragma unroll
      for (int nt = 0; nt < 4; ++nt) {
        acc[mt][nt] = __builtin_amdgcn_mfma_f32_16x16x32_bf16(
            mh[mt], dh[nt], acc[mt][nt], 0, 0, 0);
        acc[mt][nt] = __builtin_amdgcn_mfma_f32_16x16x32_bf16(
            mh[mt], dl[nt], acc[mt][nt], 0, 0, 0);
        acc[mt][nt] = __builtin_amdgcn_mfma_f32_16x16x32_bf16(
            ml[mt], dh[nt], acc[mt][nt], 0, 0, 0);
      }
    __syncthreads();
  }

  // ---- softmax over k per i-column; |30*dist| <= ~30.5 so no max-shift ----
  float tempv = temp_p[0];
#pragma unroll
  for (int mt = 0; mt < 4; ++mt)
#pragma unroll
    for (int nt = 0; nt < 4; ++nt)
#pragma unroll
      for (int reg = 0; reg < 4; ++reg)
        acc[mt][nt][reg] = __expf(tempv * acc[mt][nt][reg]);

  // per-i denominators: lane partial over its 16 k, xor over q-groups,
  // cross-wave via red[i][wave]
#pragma unroll
  for (int nt = 0; nt < 4; ++nt) {
    float s = 0.0f;
#pragma unroll
    for (int mt = 0; mt < 4; ++mt)
#pragma unroll
      for (int reg = 0; reg < 4; ++reg) s += acc[mt][nt][reg];
    s += __shfl_xor(s, 16);
    s += __shfl_xor(s, 32);
    if (q == 0) red[nt * 16 + lx][wave] = s;
  }
  __syncthreads();
  float inv_s[4];
  bool iok[4];
#pragma unroll
  for (int nt = 0; nt < 4; ++nt) {
    float4 v = *(const float4*)&red[nt * 16 + lx][0];
    inv_s[nt] = 1.0f / (v.x + v.y + v.z + v.w);
    iok[nt] = (i0 + nt * 16 + lx) < n;
  }

#pragma unroll
  for (int mt = 0; mt < 4; ++mt)
#pragma unroll
    for (int reg = 0; reg < 4; ++reg) {
      int kk = wave * 64 + mt * 16 + q * 4 + reg;
      size_t krow = (size_t)kk * n + i0;
      float csum = 0.0f;
#pragma unroll
      for (int nt = 0; nt < 4; ++nt) {
        float r = acc[mt][nt][reg] * inv_s[nt];
        acc[mt][nt][reg] = r;
        if (iok[nt]) csum += r;
      }
      csum += __shfl_xor(csum, 1);
      csum += __shfl_xor(csum, 2);
      csum += __shfl_xor(csum, 4);
      csum += __shfl_xor(csum, 8);
      if (lx == 0) atomicAdd(&colsum[kk], csum);
#pragma unroll
      for (int nt = 0; nt < 4; ++nt) {
        if (iok[nt]) {
          float r = acc[mt][nt][reg];
          short h = f2bf(r);
          r_hi[krow + nt * 16 + lx] = h;
          r_lo[krow + nt * 16 + lx] = f2bf(r - bf2f(h));
        }
      }
      if (write_f32) {
#pragma unroll
        for (int nt = 0; nt < 4; ++nt)
          if (iok[nt])
            r_f32[(size_t)(i0 + nt * 16 + lx) * KCL + kk] = acc[mt][nt][reg];
      }
    }
}

// -------- update v4: mu_acc += r^T @ data_n, all-linear async staging ------
// r planes [k][i], x planes [d][i]. Block 128 k x 128 d, 4 waves (2x2).
// global_load_lds into linear hi/lo LDS arrays; no perms, no transpose.
__global__ __launch_bounds__(256) void update_v4_k(
    const short* __restrict__ r_hi, const short* __restrict__ r_lo,
    const short* __restrict__ xT_hi, const short* __restrict__ xT_lo,
    float* __restrict__ mu_acc, int n, int chunk) {
  __shared__ __align__(16) short rh_lds[128 * 32], rl_lds[128 * 32];
  __shared__ __align__(16) short xh_lds[128 * 32], xl_lds[128 * 32];

  int t = threadIdx.x, wave = t >> 6, lane = t & 63;
  int q = lane >> 4, lx = lane & 15;
  int B = blockIdx.x;
  int x = B & 7, m = B >> 3, tt = m & 7, g = m >> 3;
  int c = x + 8 * g;  // chunk index; all 8 tiles of c share B&7 -> same XCD
  int ibeg = c * chunk;
  if (ibeg >= n) return;
  int iend = ibeg + chunk;
  if (iend > n) iend = n;  // n, chunk multiples of 32 -> full 32-i steps
  int k0 = (tt & 1) * 128, d0 = (tt >> 1) * 128;
  int wk = wave >> 1, wd = wave & 1;

  int srow = lane >> 2;
  int seg8 = (lane & 3) * 8;
  const short* rsh[2]; const short* rsl[2];
  const short* xsh[2]; const short* xsl[2];
  short *rdh[2], *rdl[2], *xdh[2], *xdl[2];
#pragma unroll
  for (int cc = 0; cc < 2; ++cc) {
    int rr = cc * 64 + wave * 16 + srow;
    rsh[cc] = r_hi + (size_t)(k0 + rr) * n + seg8;
    rsl[cc] = r_lo + (size_t)(k0 + rr) * n + seg8;
    xsh[cc] = xT_hi + (size_t)(d0 + rr) * n + seg8;
    xsl[cc] = xT_lo + (size_t)(d0 + rr) * n + seg8;
    int doff = (cc * 64 + wave * 16) * 32;
    rdh[cc] = rh_lds + doff;
    rdl[cc] = rl_lds + doff;
    xdh[cc] = xh_lds + doff;
    xdl[cc] = xl_lds + doff;
  }

  float4v acc[4][4];
#pragma unroll
  for (int mt = 0; mt < 4; ++mt)
#pragma unroll
    for (int nt = 0; nt < 4; ++nt) acc[mt][nt] = (float4v)0.0f;

  for (int ib = ibeg; ib < iend; ib += 32) {
#pragma unroll
    for (int cc = 0; cc < 2; ++cc) {
      glds16(rsh[cc] + ib, rdh[cc]);
      glds16(rsl[cc] + ib, rdl[cc]);
      glds16(xsh[cc] + ib, xdh[cc]);
      glds16(xsl[cc] + ib, xdl[cc]);
    }
    __syncthreads();
    short8 ah[4], al[4], bh[4], bl[4];
#pragma unroll
    for (int mt = 0; mt < 4; ++mt) {
      int kr = wk * 64 + mt * 16 + lx;
      ah[mt] = *(const short8*)&rh_lds[kr * 32 + q * 8];
      al[mt] = *(const short8*)&rl_lds[kr * 32 + q * 8];
    }
#pragma unroll
    for (int nt = 0; nt < 4; ++nt) {
      int dr = wd * 64 + nt * 16 + lx;
      bh[nt] = *(const short8*)&xh_lds[dr * 32 + q * 8];
      bl[nt] = *(const short8*)&xl_lds[dr * 32 + q * 8];
    }
#pragma unroll
    for (int mt = 0; mt < 4; ++mt)
#pragma unroll
      for (int nt = 0; nt < 4; ++nt) {
        acc[mt][nt] = __builtin_amdgcn_mfma_f32_16x16x32_bf16(
            ah[mt], bh[nt], acc[mt][nt], 0, 0, 0);
        acc[mt][nt] = __builtin_amdgcn_mfma_f32_16x16x32_bf16(
            ah[mt], bl[nt], acc[mt][nt], 0, 0, 0);
        acc[mt][nt] = __builtin_amdgcn_mfma_f32_16x16x32_bf16(
            al[mt], bh[nt], acc[mt][nt], 0, 0, 0);
      }
    __syncthreads();
  }
#pragma unroll
  for (int mt = 0; mt < 4; ++mt)
#pragma unroll
    for (int nt = 0; nt < 4; ++nt)
#pragma unroll
      for (int reg = 0; reg < 4; ++reg) {
        int k = k0 + wk * 64 + mt * 16 + q * 4 + reg;
        int d = d0 + wd * 64 + nt * 16 + lx;
        atomicAdd(&mu_acc[(size_t)k * DIMD + d], acc[mt][nt][reg]);
      }
}

// ==================== baseline fallback (round-0 verified) ====================
__global__ __launch_bounds__(256) void dist_base_k(
    const float* __restrict__ data, const float* __restrict__ inv_norm,
    const short* __restrict__ mu_hi, const short* __restrict__ mu_lo,
    unsigned* __restrict__ r_pack, float* __restrict__ r_f32, int write_f32,
    float* __restrict__ colsum, const float* __restrict__ temp_p, int n) {
  __shared__ __align__(16) short a_lds[64][72];
  __shared__ __align__(16) short b_lds[256][72];
  __shared__ __align__(16) float red[64][4];

  int t = threadIdx.x;
  int wave = t >> 6, lane = t & 63, q = lane >> 4, lx = lane & 15;
  int i0 = blockIdx.x * 64;

  float4v acc[4][4];
#pragma unroll
  for (int mt = 0; mt < 4; ++mt)
#pragma unroll
    for (int nt = 0; nt < 4; ++nt) acc[mt][nt] = (float4v)0.0f;

  for (int ch = 0; ch < 16; ++ch) {
    int d0 = ch * 32;
    {
      int row = t >> 2, seg = t & 3;
      int gi = i0 + row;
      if (gi > n - 1) gi = n - 1;
      const float* p = data + (size_t)gi * DIMD + d0 + seg * 8;
      float4 x0 = *(const float4*)p;
      float4 x1 = *(const float4*)(p + 4);
      float sc = inv_norm[gi];
      float vv[8] = {x0.x * sc, x0.y * sc, x0.z * sc, x0.w * sc,
                     x1.x * sc, x1.y * sc, x1.z * sc, x1.w * sc};
      short8 hv, lv;
#pragma unroll
      for (int j = 0; j < 8; ++j) {
        short h = f2bf(vv[j]);
        hv[j] = h;
        lv[j] = f2bf(vv[j] - bf2f(h));
      }
      *(short8*)&a_lds[row][seg * 8] = hv;
      *(short8*)&a_lds[row][32 + seg * 8] = lv;
    }
    {
      int seg = t & 3, kb = t >> 2;
#pragma unroll
      for (int rep = 0; rep < 4; ++rep) {
        int k = rep * 64 + kb;
        size_t o = (size_t)k * DIMD + d0 + seg * 8;
        *(short8*)&b_lds[k][seg * 8] = *(const short8*)(mu_hi + o);
        *(short8*)&b_lds[k][32 + seg * 8] = *(const short8*)(mu_lo + o);
      }
    }
    __syncthreads();
    short8 ah[4], al[4], bh[4], bl[4];
#pragma unroll
    for (int mt = 0; mt < 4; ++mt) {
      ah[mt] = *(const short8*)&a_lds[mt * 16 + lx][q * 8];
      al[mt] = *(const short8*)&a_lds[mt * 16 + lx][32 + q * 8];
    }
#pragma unroll
    for (int nt = 0; nt < 4; ++nt) {
      int kr = wave * 64 + nt * 16 + lx;
      bh[nt] = *(const short8*)&b_lds[kr][q * 8];
      bl[nt] = *(const short8*)&b_lds[kr][32 + q * 8];
    }
#pragma unroll
    for (int mt = 0; mt < 4; ++mt)
#pragma unroll
      for (int nt = 0; nt < 4; ++nt) {
        acc[mt][nt] = __builtin_amdgcn_mfma_f32_16x16x32_bf16(
            ah[mt], bh[nt], acc[mt][nt], 0, 0, 0);
        acc[mt][nt] = __builtin_amdgcn_mfma_f32_16x16x32_bf16(
            ah[mt], bl[nt], acc[mt][nt], 0, 0, 0);
        acc[mt][nt] = __builtin_amdgcn_mfma_f32_16x16x32_bf16(
            al[mt], bh[nt], acc[mt][nt], 0, 0, 0);
      }
    __syncthreads();
  }

  float tempv = temp_p[0];
  float rs[4][4];
#pragma unroll
  for (int mt = 0; mt < 4; ++mt)
#pragma unroll
    for (int reg = 0; reg < 4; ++reg) {
      float s = 0.0f;
#pragma unroll
      for (int nt = 0; nt < 4; ++nt) {
        float e = __expf(tempv * acc[mt][nt][reg]);
        acc[mt][nt][reg] = e;
        s += e;
      }
      s += __shfl_xor(s, 1);
      s += __shfl_xor(s, 2);
      s += __shfl_xor(s, 4);
      s += __shfl_xor(s, 8);
      rs[mt][reg] = s;
    }
  if (lx == 0) {
#pragma unroll
    for (int mt = 0; mt < 4; ++mt)
#pragma unroll
      for (int reg = 0; reg < 4; ++reg)
        red[mt * 16 + q * 4 + reg][wave] = rs[mt][reg];
  }
  __syncthreads();

  float cs[4] = {0.0f, 0.0f, 0.0f, 0.0f};
#pragma unroll
  for (int mt = 0; mt < 4; ++mt)
#pragma unroll
    for (int reg = 0; reg < 4; ++reg) {
      int row = mt * 16 + q * 4 + reg;
      float4 v = *(const float4*)&red[row][0];
      float is = 1.0f / (v.x + v.y + v.z + v.w);
      int gi = i0 + row;
      bool ok = gi < n;
#pragma unroll
      for (int nt = 0; nt < 4; ++nt) {
        float r = acc[mt][nt][reg] * is;
        acc[mt][nt][reg] = r;
        if (ok) cs[nt] += r;
      }
      if (ok) {
        if (write_f32) {
#pragma unroll
          for (int nt = 0; nt < 4; ++nt)
            r_f32[(size_t)gi * KCL + wave * 64 + nt * 16 + lx] =
                acc[mt][nt][reg];
        } else {
#pragma unroll
          for (int nt = 0; nt < 4; ++nt) {
            float r = acc[mt][nt][reg];
            short h = f2bf(r);
            short l = f2bf(r - bf2f(h));
            r_pack[(size_t)gi * KCL + wave * 64 + nt * 16 + lx] =
                ((unsigned)(unsigned short)h << 16) | (unsigned short)l;
          }
        }
      }
    }
#pragma unroll
  for (int nt = 0; nt < 4; ++nt) {
    cs[nt] += __shfl_xor(cs[nt], 16);
    cs[nt] += __shfl_xor(cs[nt], 32);
  }
  if (q == 0) {
#pragma unroll
    for (int nt = 0; nt < 4; ++nt)
      atomicAdd(&colsum[wave * 64 + nt * 16 + lx], cs[nt]);
  }
}

__global__ __launch_bounds__(256) void update_mfma_k(
    const unsigned* __restrict__ r_src, int r_is_f32,
    const float* __restrict__ data, const float* __restrict__ inv_norm,
    float* __restrict__ mu_acc, int n) {
  __shared__ __align__(16) short rT[128][72];
  __shared__ __align__(16) short xT[128][72];

  int t = threadIdx.x, wave = t >> 6, lane = t & 63, q = lane >> 4,
      lx = lane & 15;
  int bx = blockIdx.x;
  int k0 = (bx & 1) * 128, d0 = (bx >> 1) * 128;
  int ns = blockIdx.y;
  int chunk = (n + NSPLIT - 1) / NSPLIT;
  int ibeg = ns * chunk;
  int iend = ibeg + chunk;
  if (iend > n) iend = n;
  int wk = wave >> 1, wd = wave & 1;
  int iq = t >> 5, kq = t & 31;

  float4v acc[4][4];
#pragma unroll
  for (int mt = 0; mt < 4; ++mt)
#pragma unroll
    for (int nt = 0; nt < 4; ++nt) acc[mt][nt] = (float4v)0.0f;

  for (int ib = ibeg; ib < iend; ib += 32) {
    {
      short h[4][4], l[4][4];
#pragma unroll
      for (int ii = 0; ii < 4; ++ii) {
        int gi = ib + iq * 4 + ii;
        uint4 u = make_uint4(0u, 0u, 0u, 0u);
        if (gi < iend)
          u = *(const uint4*)(r_src + (size_t)gi * KCL + k0 + kq * 4);
        unsigned uu[4] = {u.x, u.y, u.z, u.w};
        if (r_is_f32) {
#pragma unroll
          for (int kk = 0; kk < 4; ++kk) {
            union { unsigned u; float f; } cvt; cvt.u = uu[kk];
            short hh = f2bf(cvt.f);
            h[ii][kk] = hh;
            l[ii][kk] = f2bf(cvt.f - bf2f(hh));
          }
        } else {
#pragma unroll
          for (int kk = 0; kk < 4; ++kk) {
            h[ii][kk] = (short)(uu[kk] >> 16);
            l[ii][kk] = (short)(uu[kk] & 0xffffu);
          }
        }
      }
#pragma unroll
      for (int kk = 0; kk < 4; ++kk) {
        short4v vh = {h[0][kk], h[1][kk], h[2][kk], h[3][kk]};
        short4v vl = {l[0][kk], l[1][kk], l[2][kk], l[3][kk]};
        *(short4v*)&rT[kq * 4 + kk][iq * 4] = vh;
        *(short4v*)&rT[kq * 4 + kk][32 + iq * 4] = vl;
      }
    }
    {
      short h[4][4], l[4][4];
#pragma unroll
      for (int ii = 0; ii < 4; ++ii) {
        int gi = ib + iq * 4 + ii;
        float4 xx = make_float4(0.f, 0.f, 0.f, 0.f);
        float sc = 0.0f;
        if (gi < iend) {
          xx = *(const float4*)(data + (size_t)gi * DIMD + d0 + kq * 4);
          sc = inv_norm[gi];
        }
        float vv[4] = {xx.x * sc, xx.y * sc, xx.z * sc, xx.w * sc};
#pragma unroll
        for (int kk = 0; kk < 4; ++kk) {
          short hh = f2bf(vv[kk]);
          h[ii][kk] = hh;
          l[ii][kk] = f2bf(vv[kk] - bf2f(hh));
        }
      }
#pragma unroll
      for (int kk = 0; kk < 4; ++kk) {
        short4v vh = {h[0][kk], h[1][kk], h[2][kk], h[3][kk]};
        short4v vl = {l[0][kk], l[1][kk], l[2][kk], l[3][kk]};
        *(short4v*)&xT[kq * 4 + kk][iq * 4] = vh;
        *(short4v*)&xT[kq * 4 + kk][32 + iq * 4] = vl;
      }
    }
    __syncthreads();
    short8 ah[4], al[4], bh[4], bl[4];
#pragma unroll
    for (int mt = 0; mt < 4; ++mt) {
      int kr = wk * 64 + mt * 16 + lx;
      ah[mt] = *(const short8*)&rT[kr][q * 8];
      al[mt] = *(const short8*)&rT[kr][32 + q * 8];
    }
#pragma unroll
    for (int nt = 0; nt < 4; ++nt) {
      int dr = wd * 64 + nt * 16 + lx;
      bh[nt] = *(const short8*)&xT[dr][q * 8];
      bl[nt] = *(const short8*)&xT[dr][32 + q * 8];
    }
#pragma unroll
    for (int mt = 0; mt < 4; ++mt)
#pragma unroll
      for (int nt = 0; nt < 4; ++nt) {
        acc[mt][nt] = __builtin_amdgcn_mfma_f32_16x16x32_bf16(
            ah[mt], bh[nt], acc[mt][nt], 0, 0, 0);
        acc[mt][nt] = __builtin_amdgcn_mfma_f32_16x16x32_bf16(
            ah[mt], bl[nt], acc[mt][nt], 0, 0, 0);
        acc[mt][nt] = __builtin_amdgcn_mfma_f32_16x16x32_bf16(
            al[mt], bh[nt], acc[mt][nt], 0, 0, 0);
      }
    __syncthreads();
  }
#pragma unroll
  for (int mt = 0; mt < 4; ++mt)
#pragma unroll
    for (int nt = 0; nt < 4; ++nt)
#pragma unroll
      for (int reg = 0; reg < 4; ++reg) {
        int k = k0 + wk * 64 + mt * 16 + q * 4 + reg;
        int d = d0 + wd * 64 + nt * 16 + lx;
        atomicAdd(&mu_acc[(size_t)k * DIMD + d], acc[mt][nt][reg]);
      }
}

extern "C" void kernel_launch(void* const* d_in, const int* in_sizes, int n_in,
                              void* d_out, int out_size, void* d_ws,
                              size_t ws_size, hipStream_t stream) {
  const float* embeds = (const float*)d_in[0];
  const float* temp_p = (const float*)d_in[1];
  const float* init = (const float*)d_in[2];
  int n = in_sizes[0] / DIMD;  // 100000

  float* out_mu = (float*)d_out;                       // [256*512]
  float* out_r = (float*)d_out + (size_t)KCL * DIMD;   // [n*256]

  char* base = (char*)d_ws;
  size_t off = 0;
  auto alloc = [&](size_t bytes) {
    char* p = base + off;
    off += (bytes + 255) & ~(size_t)255;
    return p;
  };
  float* inv_norm = (float*)alloc((size_t)n * 4);
  float* mu_acc = (float*)alloc((size_t)KCL * DIMD * 4);
  float* colsum = (float*)alloc(1024);
  short* mu_hi = (short*)alloc((size_t)KCL * DIMD * 2);
  short* mu_lo = (short*)alloc((size_t)KCL * DIMD * 2);

  const size_t PL = (size_t)n * DIMD * 2;   // one bf16 plane
  const size_t RTB = (size_t)n * KCL * 4;   // final-iter r hi+lo planes
  const size_t SLACK = 4096;

  short *xT_hi = nullptr, *xT_lo = nullptr, *pl_hi = nullptr, *pl_lo = nullptr;
  short* rT2 = nullptr;
  int tier = 0;
  if (off + 2 * PL + SLACK <= ws_size) {
    xT_hi = (short*)alloc(PL);
    xT_lo = (short*)alloc(PL);
    tier = 1;
  }
  if (tier == 1 && off + 2 * PL + SLACK <= ws_size) {
    pl_hi = (short*)alloc(PL);
    pl_lo = (short*)alloc(PL);
    tier = 2;
  }
  if (tier == 2 && off + RTB + SLACK <= ws_size) {
    rT2 = (short*)alloc(RTB);
    tier = 3;
  }

  row_norms_conv_k<<<(n + 3) / 4, 256, 0, stream>>>(embeds, inv_norm, pl_hi,
                                                    pl_lo, n, tier >= 3);
  if (tier >= 3)
    transpose_k<<<dim3((n + 63) / 64, DIMD / 64), 256, 0, stream>>>(
        embeds, inv_norm, xT_hi, xT_lo, n);
  mu_norm_k<<<KCL, 256, 0, stream>>>(init, colsum, mu_hi, mu_lo, mu_acc,
                                     colsum, 0);

  int dist_grid = (n + 63) / 64;

  if (tier >= 3) {
    short* r0_hi = (short*)out_r;
    short* r0_lo = r0_hi + (size_t)n * KCL;
    short* rf_hi = rT2;
    short* rf_lo = rT2 + (size_t)n * KCL;
    int chunk4 = (((n + NCH4 - 1) / NCH4) + 31) & ~31;
    for (int it = 0; it <= 10; ++it) {
      int wf32 = (it == 10) ? 1 : 0;
      short* rh = wf32 ? rf_hi : r0_hi;
      short* rl = wf32 ? rf_lo : r0_lo;
      dist_v4_k<<<dist_grid, 256, 0, stream>>>(pl_hi, pl_lo, mu_hi, mu_lo,
                                               rh, rl, out_r, wf32, colsum,
                                               temp_p, n);
      update_v4_k<<<8 * NCH4, 256, 0, stream>>>(rh, rl, xT_hi, xT_lo, mu_acc,
                                                n, chunk4);
      if (it < 10)
        mu_norm_k<<<KCL, 256, 0, stream>>>(mu_acc, colsum, mu_hi, mu_lo,
                                           mu_acc, colsum, 1);
      else
        final_mu_k<<<KCL, 256, 0, stream>>>(mu_acc, colsum, out_mu);
    }
  } else {
    for (int it = 0; it <= 10; ++it) {
      int wf32 = (it == 10) ? 1 : 0;
      dist_base_k<<<dist_grid, 256, 0, stream>>>(
          embeds, inv_norm, mu_hi, mu_lo, (unsigned*)out_r, out_r, wf32,
          colsum, temp_p, n);
      update_mfma_k<<<dim3(8, NSPLIT), 256, 0, stream>>>(
          (const unsigned*)out_r, wf32, embeds, inv_norm, mu_acc, n);
      if (it < 10)
        mu_norm_k<<<KCL, 256, 0, stream>>>(mu_acc, colsum, mu_hi, mu_lo,
                                           mu_acc, colsum, 1);
      else
        final_mu_k<<<KCL, 256, 0, stream>>>(mu_acc, colsum, out_mu);
    }
  }
}